// Round 8
// baseline (199.816 us; speedup 1.0000x reference)
//
#include <hip/hip_runtime.h>

// QuantFinanceAttention: B=2, T=2048, C=1024, H=16, dk=64. fp32 I/O, bf16 MFMA internals.
// cvt(all, writes x in A-FRAGMENT-major + Wq/Wk/Wv in B-FRAGMENT-major, Wo row-major) |
// QKV gemm v3: NO LDS, NO barriers -- every MFMA operand is one coalesced 1KB/wave
// global load from L2-resident fragment-major tensors (flash-v6 pattern applied to the
// GEMM; the 48KB-LDS barrier-lockstep version was stuck at 21% MfmaUtil with all pipes
// idle). Rope fused; K pre-scaled by SCALE*log2e*sector_w; Q/K/V written fragment-major
// for flash | flash v6 (no LDS, in-register softmax) | proj (3-buf counted-vmcnt LDS).

typedef __bf16 bf16x8 __attribute__((ext_vector_type(8)));
typedef float f32x4 __attribute__((ext_vector_type(4)));
typedef float f32x16 __attribute__((ext_vector_type(16)));
typedef unsigned short u16x8 __attribute__((ext_vector_type(8)));

__device__ __forceinline__ unsigned short f2bf(float f) {
    union { float f; unsigned int u; } c; c.f = f;
    unsigned int u = c.u;
    unsigned int r = u + 0x7fffu + ((u >> 16) & 1u);  // RNE
    return (unsigned short)(r >> 16);
}
__device__ __forceinline__ unsigned cvtpk(float lo, float hi) {
    unsigned r;
    asm("v_cvt_pk_bf16_f32 %0, %1, %2" : "=v"(r) : "v"(lo), "v"(hi));
    return r;
}
// Exchange across the lane<32 / lane>=32 halves:
//   ret0[l<32]=a[l], ret0[l>=32]=b[l-32];  ret1[l<32]=a[l+32], ret1[l>=32]=b[l]
__device__ __forceinline__ void plswap(unsigned a, unsigned b, unsigned& r0, unsigned& r1) {
#if __has_builtin(__builtin_amdgcn_permlane32_swap)
    auto s = __builtin_amdgcn_permlane32_swap(a, b, false, false);
    r0 = (unsigned)s[0]; r1 = (unsigned)s[1];
#else
    const int hh = (int)(threadIdx.x & 63) >> 5;
    const unsigned oa = (unsigned)__shfl_xor((int)a, 32);
    const unsigned ob = (unsigned)__shfl_xor((int)b, 32);
    r0 = hh ? ob : a;
    r1 = hh ? b : oa;
#endif
}
__device__ __forceinline__ void stage8_f32(unsigned short* dst, const float* src) {
    const float4 a = *(const float4*)src;
    const float4 b = *(const float4*)(src + 4);
    u16x8 v;
    v[0] = f2bf(a.x); v[1] = f2bf(a.y); v[2] = f2bf(a.z); v[3] = f2bf(a.w);
    v[4] = f2bf(b.x); v[5] = f2bf(b.y); v[6] = f2bf(b.z); v[7] = f2bf(b.w);
    *(u16x8*)dst = v;
}
__device__ __forceinline__ void async16(const unsigned short* g, unsigned short* l) {
    __builtin_amdgcn_global_load_lds(
        (const __attribute__((address_space(1))) void*)g,
        (__attribute__((address_space(3))) void*)l, 16, 0, 0);
}

// Fragment-major layout (shorts), used for x (A-side) and Wq/Wk/Wv (B-side):
//   addr(row, k) = (row>>4)*16384 + (k>>5)*512 + ((k>>3)&3)*128 + (row&15)*8 + (k&7)
// -> a wave's 16-lane fragment read (lane l, k-chunk g) is 256B contiguous; the 64-lane
//    bf16x8 load covers 1KB contiguous. cvt write side: dst g8 index i decodes as
//    lane16=i&15, sub=(i>>4)&3, kb=(i>>6)&31, rb=i>>11; src g8 = (rb*16+lane16)*128+kb*4+sub.
//    A wave's 64 src reads exactly tile rows rb*16..+15 x 128B -> no HBM over-fetch.
__global__ __launch_bounds__(256) void cvt_all(
    const float* __restrict__ x, const float* __restrict__ Wq, const float* __restrict__ Wk,
    const float* __restrict__ Wv, const float* __restrict__ Wo,
    unsigned short* __restrict__ dst, int hasX, int n8)
{
    const int i = blockIdx.x * 256 + threadIdx.x;
    if (i >= n8) return;
    int r = i;
    const float* src; size_t soff;
    const int xg = hasX ? 524288 : 0;
    if (r < xg) {                            // x -> A-fragment-major (big path only)
        const int lane16 = r & 15, sub = (r >> 4) & 3, kb = (r >> 6) & 31, rb = r >> 11;
        src = x; soff = (size_t)(rb * 16 + lane16) * 128 + kb * 4 + sub;
    } else {
        r -= xg;
        const int w = r >> 17, o = r & 131071;
        src = (w == 0) ? Wq : (w == 1) ? Wk : (w == 2) ? Wv : Wo;
        if (hasX && w < 3) {                 // Wq/Wk/Wv -> B-fragment-major
            const int lane16 = o & 15, sub = (o >> 4) & 3, kb = (o >> 6) & 31, nb = o >> 11;
            soff = (size_t)(nb * 16 + lane16) * 128 + kb * 4 + sub;
        } else {
            soff = o;                        // Wo (and fallback path): row-major
        }
    }
    stage8_f32(&dst[(size_t)i * 8], &src[soff * 8]);
}

// Flash fragment layouts (per bh = 131072 shorts), written by the epilogue:
//  Q/K: addr = bh*131072 + ((t>>5)*4 + (d>>4))*512 + (((d>>3)&1)*32 + (t&31))*8 + (d&7)
//  V:   addr = bh*131072 + ((t>>5)*4 + (d>>5)*2 + ((t>>4)&1))*512 + (((t>>3)&1)*32 + (d&31))*8 + (t&7)
template<int A_BF16>
__global__ __launch_bounds__(256) void gemm_qkv(
    const void* __restrict__ Av, const unsigned short* __restrict__ Wb,
    unsigned short* __restrict__ outv, const float* __restrict__ swg)
{
    constexpr int K = 1024, BK = 32;
    const int tid = threadIdx.x;
    const int wid = tid >> 6, lane = tid & 63, g = lane >> 4, l = lane & 15;
    const int wm = (wid & 1) * 64, wn = (wid >> 1) * 64;

    // XCD-chunked bijective swizzle (768 blocks, 768%8==0)
    const int lin = blockIdx.x + (blockIdx.y << 3) + (blockIdx.z << 8);
    const int wg  = (lin & 7) * 96 + (lin >> 3);
    const int bx = wg & 7, by = (wg >> 3) & 31, bz = wg >> 8;
    const int m0 = by * 128, n0 = bx * 128;
    const int z = bz;
    const unsigned short* W = Wb + (size_t)z * 1048576;

    f32x4 acc[4][4];
#pragma unroll
    for (int i = 0; i < 4; ++i)
#pragma unroll
        for (int j = 0; j < 4; ++j) acc[i][j] = f32x4{0.f, 0.f, 0.f, 0.f};

    if constexpr (A_BF16) {
        // ---- no-LDS fragment-streaming K-loop (flash-v6 pattern) ----
        const unsigned short* A = (const unsigned short*)Av;
        const unsigned short* Ab = A + (size_t)((m0 + wm) >> 4) * 16384 + g * 128 + l * 8;
        const unsigned short* Bb = W + (size_t)((n0 + wn) >> 4) * 16384 + g * 128 + l * 8;
#pragma unroll 2
        for (int kb = 0; kb < 32; ++kb) {
            bf16x8 af[4], bfr[4];
#pragma unroll
            for (int im = 0; im < 4; ++im)
                af[im]  = *(const bf16x8*)(Ab + (size_t)im * 16384 + kb * 512);
#pragma unroll
            for (int in = 0; in < 4; ++in)
                bfr[in] = *(const bf16x8*)(Bb + (size_t)in * 16384 + kb * 512);
#pragma unroll
            for (int im = 0; im < 4; ++im)
#pragma unroll
                for (int in = 0; in < 4; ++in)
                    acc[im][in] = __builtin_amdgcn_mfma_f32_16x16x32_bf16(af[im], bfr[in], acc[im][in], 0, 0, 0);
        }
    } else {
        // ---- fallback: fp32 A + row-major W, 2-buffer syncthreads LDS loop ----
        __shared__ __align__(16) unsigned short As[2][128 * BK];
        __shared__ __align__(16) unsigned short Bs[2][128 * BK];
        const int r  = tid >> 2;
        const int cs = (((tid & 3) ^ ((tid >> 3) & 3)) * 8);  // pre-swizzled source chunk
        const int xg = (g ^ ((l >> 1) & 3)) * 8;              // read-side chunk
        const unsigned short* Wg0 = &W[(size_t)(n0 + r) * K + cs];
        const unsigned short* Wg1 = Wg0 + (size_t)64 * K;
        auto stageF = [&](int buf, int k0) {
            const float* A = (const float*)Av;
            stage8_f32(&As[buf][(tid >> 2) * BK + cs],        &A[(size_t)(m0 + r) * K + k0 + cs]);
            stage8_f32(&As[buf][(tid >> 2) * BK + cs + 2048], &A[(size_t)(m0 + 64 + r) * K + k0 + cs]);
            unsigned short* BsW = &Bs[buf][wid * 512];
            async16(Wg0 + k0, BsW);
            async16(Wg1 + k0, BsW + 2048);
        };
        stageF(0, 0);
        __syncthreads();
        for (int k0 = 0; k0 < K; k0 += BK) {
            const int cur = (k0 >> 5) & 1;
            if (k0 + BK < K) stageF(cur ^ 1, k0 + BK);
            bf16x8 af[4], bfr[4];
#pragma unroll
            for (int im = 0; im < 4; ++im) af[im]  = *(const bf16x8*)&As[cur][(wm + im * 16 + l) * BK + xg];
#pragma unroll
            for (int in = 0; in < 4; ++in) bfr[in] = *(const bf16x8*)&Bs[cur][(wn + in * 16 + l) * BK + xg];
#pragma unroll
            for (int im = 0; im < 4; ++im)
#pragma unroll
                for (int in = 0; in < 4; ++in)
                    acc[im][in] = __builtin_amdgcn_mfma_f32_16x16x32_bf16(af[im], bfr[in], acc[im][in], 0, 0, 0);
            __syncthreads();
        }
    }

    unsigned short* outq = outv + (size_t)z * 4194304;
    if (z < 2) {
        const int hq = (n0 + wn) >> 6;               // head (constant per thread)
        float freq[2];
#pragma unroll
        for (int in = 0; in < 2; ++in)
            freq[in] = exp2f(-(float)(in * 16 + l) * 0.41524101186f);  // log2(10000)/32
#pragma unroll
        for (int im = 0; im < 4; ++im)
#pragma unroll
            for (int i = 0; i < 4; ++i) {
                const int m = m0 + wm + im * 16 + (lane >> 4) * 4 + i;
                const int b = m >> 11, t = m & 2047;
                float fw = 1.0f;
                if (z == 1) fw = 0.18033688011f * swg[(b << 11) + t];  // SCALE*log2(e)*w
                const size_t fq = (size_t)((b << 4) + hq) * 131072
                                + (size_t)((t >> 5) << 2) * 512
                                + (size_t)((((l >> 3) & 1) << 5) + (t & 31)) * 8 + (l & 7);
#pragma unroll
                for (int in = 0; in < 2; ++in) {
                    const float ang = (float)t * freq[in];
                    const float cs2 = __cosf(ang), sn = __sinf(ang);
                    const float x1 = acc[im][in][i], x2 = acc[im][in + 2][i];
                    outq[fq + (size_t)in * 512]       = f2bf((x1 * cs2 - x2 * sn) * fw);
                    outq[fq + (size_t)(in + 2) * 512] = f2bf((x2 * cs2 + x1 * sn) * fw);
                }
            }
    } else {
        // V fragments: 4 consecutive t -> 4 consecutive slots within one lane group -> ushort4
#pragma unroll
        for (int im = 0; im < 4; ++im)
#pragma unroll
            for (int in = 0; in < 4; ++in) {
                const int n = n0 + wn + in * 16 + l;
                const int h = n >> 6, d = n & 63;
                const int mb = m0 + wm + im * 16 + (lane >> 4) * 4;
                const int bq = mb >> 11, t0 = mb & 2047;
                ushort4 pk;
                pk.x = f2bf(acc[im][in][0]); pk.y = f2bf(acc[im][in][1]);
                pk.z = f2bf(acc[im][in][2]); pk.w = f2bf(acc[im][in][3]);
                const size_t fv = (size_t)((bq << 4) + h) * 131072
                                + (size_t)(((t0 >> 5) << 2) + ((d >> 5) << 1) + ((t0 >> 4) & 1)) * 512
                                + (size_t)((((t0 >> 3) & 1) << 5) + (d & 31)) * 8 + (t0 & 7);
                *(ushort4*)&outq[fv] = pk;
            }
    }
}

// Projection: C = A(bf16)[4096,1024] x Wo^T + bias, 64x128 tile -> 512 blocks.
// 3-buffer counted-vmcnt pipeline (3 loads/thread/stage -> vmcnt(3)), unrolled x3,
// LDS chunk swizzle (conflict-free).
__global__ __launch_bounds__(256) void gemm_proj(
    const unsigned short* __restrict__ A, const unsigned short* __restrict__ W,
    float* __restrict__ out, const float* __restrict__ bias)
{
    constexpr int K = 1024, BK = 32;
    __shared__ __align__(16) unsigned short As[3][64 * BK];
    __shared__ __align__(16) unsigned short Bs[3][128 * BK];
    const int tid = threadIdx.x;
    const int wid = tid >> 6, lane = tid & 63, g = lane >> 4, l = lane & 15;
    const int wm = (wid & 1) * 32, wn = (wid >> 1) * 64;

    const int lin = blockIdx.x + (blockIdx.y << 3);     // 512 blocks, 512%8==0
    const int wg  = (lin & 7) * 64 + (lin >> 3);
    const int m0 = (wg >> 3) * 64, n0 = (wg & 7) * 128;

    f32x4 acc[2][4];
#pragma unroll
    for (int i = 0; i < 2; ++i)
#pragma unroll
        for (int j = 0; j < 4; ++j) acc[i][j] = f32x4{0.f, 0.f, 0.f, 0.f};

    const int r  = tid >> 2;
    const int cs = (((tid & 3) ^ ((tid >> 3) & 3)) * 8);
    const int xg = (g ^ ((l >> 1) & 3)) * 8;
    int aoff[2], boff[4];
#pragma unroll
    for (int im = 0; im < 2; ++im) aoff[im] = (wm + im * 16 + l) * BK + xg;
#pragma unroll
    for (int in = 0; in < 4; ++in) boff[in] = (wn + in * 16 + l) * BK + xg;

    const unsigned short* Ag0 = &A[(size_t)(m0 + r) * K + cs];
    const unsigned short* Wg0 = &W[(size_t)(n0 + r) * K + cs];
    const unsigned short* Wg1 = Wg0 + (size_t)64 * K;

    auto stage = [&](int buf, int k0) {
        async16(Ag0 + k0, &As[buf][wid * 512]);
        unsigned short* BsW = &Bs[buf][wid * 512];
        async16(Wg0 + k0, BsW);
        async16(Wg1 + k0, BsW + 2048);
    };
    auto compute = [&](int buf) {
        bf16x8 af[2], bfr[4];
#pragma unroll
        for (int im = 0; im < 2; ++im) af[im]  = *(const bf16x8*)&As[buf][aoff[im]];
#pragma unroll
        for (int in = 0; in < 4; ++in) bfr[in] = *(const bf16x8*)&Bs[buf][boff[in]];
#pragma unroll
        for (int im = 0; im < 2; ++im)
#pragma unroll
            for (int in = 0; in < 4; ++in)
                acc[im][in] = __builtin_amdgcn_mfma_f32_16x16x32_bf16(af[im], bfr[in], acc[im][in], 0, 0, 0);
    };

    stage(0, 0);
    stage(1, BK);
    for (int t = 0; t < 10; ++t) {
        const int tb = t * 96;
#pragma unroll
        for (int u = 0; u < 3; ++u) {
            asm volatile("s_waitcnt vmcnt(3)" ::: "memory");
            __builtin_amdgcn_s_barrier();
            compute(u);
            stage((u + 2) % 3, tb + (u + 2) * BK);
        }
    }
    asm volatile("s_waitcnt vmcnt(3)" ::: "memory");   // ks=30
    __builtin_amdgcn_s_barrier();
    compute(0);
    asm volatile("s_waitcnt vmcnt(0)" ::: "memory");   // ks=31
    __builtin_amdgcn_s_barrier();
    compute(1);

#pragma unroll
    for (int im = 0; im < 2; ++im)
#pragma unroll
        for (int in = 0; in < 4; ++in) {
            const int n = n0 + wn + in * 16 + l;
#pragma unroll
            for (int i = 0; i < 4; ++i) {
                const int m = m0 + wm + im * 16 + g * 4 + i;
                out[(size_t)m * 1024 + n] = acc[im][in][i] + bias[n];
            }
        }
}

// Flash v6: 2048 blocks x 128 threads, block = (bh, 32q strip p), longest-first.
// NO LDS staging, NO barriers in the loop: Q/K/V pre-fragmented so each MFMA operand
// is one coalesced 16B/lane global load (L2/L3-resident). Wave wid owns key chunks
// c = wid, wid+2, ... <= p. Swapped QK^T -> in-register softmax (16 exp2 + 8 cvt_pk
// + 4 permlane32_swap). K pre-scaled by SCALE*log2e*w[key]. Constant-max softmax ->
// the two waves' partials combine additively once at the end (12KB LDS).
__global__ __launch_bounds__(128, 2) void flash_attn(
    const unsigned short* __restrict__ Qf, const unsigned short* __restrict__ Kf,
    const unsigned short* __restrict__ Vf, const float* __restrict__ sbias,
    const float* __restrict__ sw, unsigned short* __restrict__ attn)
{
    constexpr int T = 2048;
    __shared__ float Cmb[3072];             // 2x16x64 oacc + 16x64 lrow = 12 KB

    const int tid = threadIdx.x, wid = tid >> 6, lane = tid & 63;
    const int hl = lane & 31, hh = lane >> 5;
    const int id = blockIdx.x;
    const int p  = 63 - (id >> 5);          // globally longest-first
    const int bh = id & 31, b = bh >> 4, h = bh & 15;
    const size_t fb = (size_t)bh * 131072;  // fragment base (Q/K/V identical shape)
    const float bias = sbias[h];
    const float* swb = sw + b * T;

    bf16x8 onef;
#pragma unroll
    for (int j = 0; j < 8; ++j) onef[j] = (__bf16)1.0f;

    const int q0 = p * 32;
    bf16x8 qf[4];
#pragma unroll
    for (int ks = 0; ks < 4; ++ks)
        qf[ks] = *(const bf16x8*)&Qf[fb + (size_t)(p * 4 + ks) * 512 + lane * 8];

    f32x16 oacc[2], lrow;
#pragma unroll
    for (int r = 0; r < 16; ++r) { oacc[0][r] = 0.f; oacc[1][r] = 0.f; lrow[r] = 0.f; }

    for (int c = wid; c <= p; c += 2) {
        const unsigned short* kb = &Kf[fb + (size_t)c * 2048 + lane * 8];
        const unsigned short* vb = &Vf[fb + (size_t)c * 2048 + lane * 8];

        // S^T = K' Q^T (32k x 32q): lane holds q = q0+hl, rows r -> keys
        const bf16x8 kf0 = *(const bf16x8*)&kb[0];
        const bf16x8 kf1 = *(const bf16x8*)&kb[512];
        const bf16x8 kf2 = *(const bf16x8*)&kb[1024];
        const bf16x8 kf3 = *(const bf16x8*)&kb[1536];
        f32x16 sx;
#pragma unroll
        for (int r = 0; r < 16; ++r) sx[r] = 0.f;
        sx = __builtin_amdgcn_mfma_f32_32x32x16_bf16(kf0, qf[0], sx, 0, 0, 0);
        sx = __builtin_amdgcn_mfma_f32_32x32x16_bf16(kf1, qf[1], sx, 0, 0, 0);
        sx = __builtin_amdgcn_mfma_f32_32x32x16_bf16(kf2, qf[2], sx, 0, 0, 0);
        sx = __builtin_amdgcn_mfma_f32_32x32x16_bf16(kf3, qf[3], sx, 0, 0, 0);

        // issue V loads now; softmax below covers their L2 latency
        const bf16x8 vf00 = *(const bf16x8*)&vb[0];      // (dt0,ks0)
        const bf16x8 vf01 = *(const bf16x8*)&vb[512];    // (dt0,ks1)
        const bf16x8 vf10 = *(const bf16x8*)&vb[1024];   // (dt1,ks0)
        const bf16x8 vf11 = *(const bf16x8*)&vb[1536];   // (dt1,ks1)

        if (bias != 0.0f) {                  // benchmark has sector_bias == 0
            const float bn = bias * 1.44269504f;
#pragma unroll
            for (int r = 0; r < 16; ++r) {
                const int kl = (r & 3) + 8 * (r >> 2) + 4 * hh;
                sx[r] += bn * swb[c * 32 + kl];
            }
        }
        if (c == p) {                        // diagonal chunk: causal mask (key kl <= q hl)
#pragma unroll
            for (int r = 0; r < 16; ++r) {
                const int kl = (r & 3) + 8 * (r >> 2) + 4 * hh;
                sx[r] = (kl <= hl) ? sx[r] : -1e30f;
            }
        }
#pragma unroll
        for (int r = 0; r < 16; ++r) sx[r] = exp2f(sx[r]);

        // pack P -> bf16 A-fragment: 8 cvt_pk + 4 permlane32_swap
        unsigned wds[8];
#pragma unroll
        for (int g2 = 0; g2 < 4; ++g2) {
            wds[g2 * 2]     = cvtpk(sx[g2 * 4],     sx[g2 * 4 + 1]);
            wds[g2 * 2 + 1] = cvtpk(sx[g2 * 4 + 2], sx[g2 * 4 + 3]);
        }
        bf16x8 pf[2];
#pragma unroll
        for (int ks = 0; ks < 2; ++ks) {
            unsigned a0, a1, b0, b1;
            plswap(wds[4 * ks],     wds[4 * ks + 2], a0, a1);
            plswap(wds[4 * ks + 1], wds[4 * ks + 3], b0, b1);
            union { unsigned u[4]; bf16x8 v; } pk_;
            pk_.u[0] = a0; pk_.u[1] = b0;
            pk_.u[2] = a1; pk_.u[3] = b1;
            pf[ks] = pk_.v;
        }

        // rowsum via ones-MFMA, accumulated straight into lrow
        lrow = __builtin_amdgcn_mfma_f32_32x32x16_bf16(pf[0], onef, lrow, 0, 0, 0);
        lrow = __builtin_amdgcn_mfma_f32_32x32x16_bf16(pf[1], onef, lrow, 0, 0, 0);

        // O += P V
        oacc[0] = __builtin_amdgcn_mfma_f32_32x32x16_bf16(pf[0], vf00, oacc[0], 0, 0, 0);
        oacc[0] = __builtin_amdgcn_mfma_f32_32x32x16_bf16(pf[1], vf01, oacc[0], 0, 0, 0);
        oacc[1] = __builtin_amdgcn_mfma_f32_32x32x16_bf16(pf[0], vf10, oacc[1], 0, 0, 0);
        oacc[1] = __builtin_amdgcn_mfma_f32_32x32x16_bf16(pf[1], vf11, oacc[1], 0, 0, 0);
    }

    // combine the two waves' partials (additive under constant-max softmax)
    __syncthreads();
    if (wid == 1) {
#pragma unroll
        for (int dt = 0; dt < 2; ++dt)
#pragma unroll
            for (int r = 0; r < 16; ++r) Cmb[(dt * 16 + r) * 64 + lane] = oacc[dt][r];
#pragma unroll
        for (int r = 0; r < 16; ++r) Cmb[2048 + r * 64 + lane] = lrow[r];
    }
    __syncthreads();
    if (wid == 0) {
#pragma unroll
        for (int r = 0; r < 16; ++r) {
            const float li = 1.0f / (lrow[r] + Cmb[2048 + r * 64 + lane]);
            const int row = (r & 3) + 8 * (r >> 2) + 4 * hh;
            const int qr = q0 + row;
#pragma unroll
            for (int dt = 0; dt < 2; ++dt) {
                const float ov = oacc[dt][r] + Cmb[(dt * 16 + r) * 64 + lane];
                attn[(size_t)(b * T + qr) * 1024 + h * 64 + dt * 32 + hl] = f2bf(ov * li);
            }
        }
    }
}

extern "C" void kernel_launch(void* const* d_in, const int* in_sizes, int n_in,
                              void* d_out, int out_size, void* d_ws, size_t ws_size,
                              hipStream_t stream) {
    const float* x  = (const float*)d_in[0];
    const float* Wq = (const float*)d_in[1];
    const float* Wk = (const float*)d_in[2];
    const float* Wv = (const float*)d_in[3];
    const float* Wo = (const float*)d_in[4];
    const float* bo = (const float*)d_in[5];
    const float* sb = (const float*)d_in[6];
    const float* sw = (const float*)d_in[7];

    const size_t QKV_SZ = 4194304;   // shorts per q/k/v tensor
    const size_t W_SZ   = 1048576;   // shorts per weight matrix
    unsigned short* ws16 = (unsigned short*)d_ws;
    const bool big = ws_size >= 2 * (4 * QKV_SZ + 4 * W_SZ);  // 41.9 MB

    if (big) {
        unsigned short* xb    = ws16;            // x (A-fragment-major)
        unsigned short* Wb3   = xb + QKV_SZ;     // Wq,Wk,Wv (B-fragment-major)
        unsigned short* Wob   = Wb3 + 3 * W_SZ;  // Wo (row-major)
        unsigned short* qkv   = Wob + W_SZ;      // q,k,v (flash-fragment-major)
        unsigned short* attnb = xb;              // overlay x (dead after QKV gemm)

        cvt_all<<<4096, 256, 0, stream>>>(x, Wq, Wk, Wv, Wo, xb, 1, 1048576);
        gemm_qkv<1><<<dim3(8, 32, 3), 256, 0, stream>>>(xb, Wb3, qkv, sw);
        flash_attn<<<2048, 128, 0, stream>>>(qkv, qkv + QKV_SZ, qkv + 2 * QKV_SZ,
                                             sb, sw, attnb);
        gemm_proj<<<dim3(8, 64), 256, 0, stream>>>(attnb, Wob, (float*)d_out, bo);
    } else {                                     // 33.6 MB fallback
        unsigned short* qkv   = ws16;
        unsigned short* attnb = qkv + 3 * QKV_SZ;
        unsigned short* Wb3   = attnb;           // overlay attn (dead until flash)
        unsigned short* Wob   = qkv;             // overlay q (dead after flash)

        cvt_all<<<1536, 256, 0, stream>>>(x, Wq, Wk, Wv, Wo, Wb3, 0, 393216);
        gemm_qkv<0><<<dim3(8, 32, 3), 256, 0, stream>>>(x, Wb3, qkv, sw);
        flash_attn<<<2048, 128, 0, stream>>>(qkv, qkv + QKV_SZ, qkv + 2 * QKV_SZ,
                                             sb, sw, attnb);
        cvt_all<<<512, 256, 0, stream>>>(x, Wo, Wo, Wo, Wo, Wob, 0, 131072);
        gemm_proj<<<dim3(8, 64), 256, 0, stream>>>(attnb, Wob, (float*)d_out, bo);
    }
}

// Round 9
// 184.706 us; speedup vs baseline: 1.0818x; 1.0818x over previous
//
#include <hip/hip_runtime.h>

// QuantFinanceAttention: B=2, T=2048, C=1024, H=16, dk=64. fp32 I/O, bf16 MFMA internals.
// cvt(all) | QKV gemm v5: 512-thread / 8-wave blocks (24 waves/CU, 2x TLP vs the 256-thr
// version whose every pipe sat <50% busy -- latency-bound), 3-buffer counted-vmcnt(2)
// pipeline, XCD swizzle, rope fused, K pre-scaled by SCALE*log2e*sector_w, Q/K/V written
// FRAGMENT-MAJOR for flash | flash v6 (no LDS staging, in-register softmax) | proj
// (3-buf counted-vmcnt). NOTE: no-LDS GEMM (r8) regressed -- GEMM needs LDS reuse;
// conflict/VALU micro-fixes (r7) moved counters but not time -- not the critical path.

typedef __bf16 bf16x8 __attribute__((ext_vector_type(8)));
typedef float f32x4 __attribute__((ext_vector_type(4)));
typedef float f32x16 __attribute__((ext_vector_type(16)));
typedef unsigned short u16x8 __attribute__((ext_vector_type(8)));

__device__ __forceinline__ unsigned short f2bf(float f) {
    union { float f; unsigned int u; } c; c.f = f;
    unsigned int u = c.u;
    unsigned int r = u + 0x7fffu + ((u >> 16) & 1u);  // RNE
    return (unsigned short)(r >> 16);
}
__device__ __forceinline__ unsigned cvtpk(float lo, float hi) {
    unsigned r;
    asm("v_cvt_pk_bf16_f32 %0, %1, %2" : "=v"(r) : "v"(lo), "v"(hi));
    return r;
}
// Exchange across the lane<32 / lane>=32 halves:
//   ret0[l<32]=a[l], ret0[l>=32]=b[l-32];  ret1[l<32]=a[l+32], ret1[l>=32]=b[l]
__device__ __forceinline__ void plswap(unsigned a, unsigned b, unsigned& r0, unsigned& r1) {
#if __has_builtin(__builtin_amdgcn_permlane32_swap)
    auto s = __builtin_amdgcn_permlane32_swap(a, b, false, false);
    r0 = (unsigned)s[0]; r1 = (unsigned)s[1];
#else
    const int hh = (int)(threadIdx.x & 63) >> 5;
    const unsigned oa = (unsigned)__shfl_xor((int)a, 32);
    const unsigned ob = (unsigned)__shfl_xor((int)b, 32);
    r0 = hh ? ob : a;
    r1 = hh ? b : oa;
#endif
}
__device__ __forceinline__ void stage8_f32(unsigned short* dst, const float* src) {
    const float4 a = *(const float4*)src;
    const float4 b = *(const float4*)(src + 4);
    u16x8 v;
    v[0] = f2bf(a.x); v[1] = f2bf(a.y); v[2] = f2bf(a.z); v[3] = f2bf(a.w);
    v[4] = f2bf(b.x); v[5] = f2bf(b.y); v[6] = f2bf(b.z); v[7] = f2bf(b.w);
    *(u16x8*)dst = v;
}
__device__ __forceinline__ void async16(const unsigned short* g, unsigned short* l) {
    __builtin_amdgcn_global_load_lds(
        (const __attribute__((address_space(1))) void*)g,
        (__attribute__((address_space(3))) void*)l, 16, 0, 0);
}

// Fused fp32->bf16 convert. dst layout: [x(524288 g8) if hasX][Wq][Wk][Wv][Wo] (131072 g8 each).
__global__ __launch_bounds__(256) void cvt_all(
    const float* __restrict__ x, const float* __restrict__ Wq, const float* __restrict__ Wk,
    const float* __restrict__ Wv, const float* __restrict__ Wo,
    unsigned short* __restrict__ dst, int hasX, int n8)
{
    const int i = blockIdx.x * 256 + threadIdx.x;
    if (i >= n8) return;
    int r = i;
    const float* src; int off;
    const int xg = hasX ? 524288 : 0;
    if (r < xg) { src = x; off = r; }
    else {
        r -= xg;
        const int w = r >> 17, o = r & 131071;
        src = (w == 0) ? Wq : (w == 1) ? Wk : (w == 2) ? Wv : Wo;
        off = o;
    }
    stage8_f32(&dst[(size_t)i * 8], &src[(size_t)off * 8]);
}

// Flash fragment layouts (per bh = 131072 shorts), written by the epilogue:
//  Q/K: addr = bh*131072 + ((t>>5)*4 + (d>>4))*512 + (((d>>3)&1)*32 + (t&31))*8 + (d&7)
//  V:   addr = bh*131072 + ((t>>5)*4 + (d>>5)*2 + ((t>>4)&1))*512 + (((t>>3)&1)*32 + (d&31))*8 + (t&7)
// 512 threads / 8 waves: wave (wid&3, wid>>2) owns a 32x64 sub-tile (n kept 64-wide so
// the rope pair d/d+32 stays wave-local). Staging: 1 A + 1 B async16 per thread per
// stage -> counted wait vmcnt(2) keeps next stage's loads in flight across the barrier.
template<int A_BF16>
__global__ __launch_bounds__(512) void gemm_qkv(
    const void* __restrict__ Av, const unsigned short* __restrict__ Wb,
    unsigned short* __restrict__ outv, const float* __restrict__ swg)
{
    constexpr int K = 1024, BK = 32, NS = K / BK;
    __shared__ __align__(16) unsigned short As[3][128 * BK];
    __shared__ __align__(16) unsigned short Bs[3][128 * BK];
    const int tid = threadIdx.x;
    const int wid = tid >> 6, lane = tid & 63, g = lane >> 4, l = lane & 15;
    const int wm = (wid & 3) * 32, wn = (wid >> 2) * 64;

    // XCD-chunked bijective swizzle (768 blocks, 768%8==0)
    const int lin = blockIdx.x + (blockIdx.y << 3) + (blockIdx.z << 8);
    const int wg  = (lin & 7) * 96 + (lin >> 3);
    const int bx = wg & 7, by = (wg >> 3) & 31, bz = wg >> 8;
    const int m0 = by * 128, n0 = bx * 128;
    const int z = bz;
    const unsigned short* W = Wb + (size_t)z * 1048576;

    f32x4 acc[2][4];
#pragma unroll
    for (int i = 0; i < 2; ++i)
#pragma unroll
        for (int j = 0; j < 4; ++j) acc[i][j] = f32x4{0.f, 0.f, 0.f, 0.f};

    const int r = tid >> 2;            // staged row 0..127 (wave w: rows 16w..16w+15)
    const int c = (tid & 3) * 8;       // staged k-chunk

    auto compute = [&](int buf) {
        const unsigned short* Asr = As[buf];
        const unsigned short* Bsr = Bs[buf];
        bf16x8 af[2], bfr[4];
#pragma unroll
        for (int im = 0; im < 2; ++im) af[im]  = *(const bf16x8*)&Asr[(wm + im * 16 + l) * BK + g * 8];
#pragma unroll
        for (int in = 0; in < 4; ++in) bfr[in] = *(const bf16x8*)&Bsr[(wn + in * 16 + l) * BK + g * 8];
#pragma unroll
        for (int im = 0; im < 2; ++im)
#pragma unroll
            for (int in = 0; in < 4; ++in)
                acc[im][in] = __builtin_amdgcn_mfma_f32_16x16x32_bf16(af[im], bfr[in], acc[im][in], 0, 0, 0);
    };

    if (A_BF16) {
        const unsigned short* A = (const unsigned short*)Av;
        auto stage = [&](int buf, int k0) {
            async16(&A[(size_t)(m0 + r) * K + k0 + c], &As[buf][wid * 512]);
            async16(&W[(size_t)(n0 + r) * K + k0 + c], &Bs[buf][wid * 512]);
        };
        stage(0, 0);
        stage(1, BK);
        for (int ks = 0; ks < NS; ++ks) {
            if (ks + 1 < NS) asm volatile("s_waitcnt vmcnt(2)" ::: "memory");
            else             asm volatile("s_waitcnt vmcnt(0)" ::: "memory");
            __builtin_amdgcn_s_barrier();
            compute(ks % 3);
            if (ks + 2 < NS) stage((ks + 2) % 3, (ks + 2) * BK);
        }
    } else {
        // fallback: fp32 A staged through registers; 2-buffer syncthreads loop
        auto stageF = [&](int buf, int k0) {
            const float* A = (const float*)Av;
            stage8_f32(&As[buf][r * BK + c], &A[(size_t)(m0 + r) * K + k0 + c]);
            async16(&W[(size_t)(n0 + r) * K + k0 + c], &Bs[buf][wid * 512]);
        };
        stageF(0, 0);
        __syncthreads();
        for (int k0 = 0; k0 < K; k0 += BK) {
            const int cur = (k0 >> 5) & 1;
            if (k0 + BK < K) stageF(cur ^ 1, k0 + BK);
            compute(cur);
            __syncthreads();
        }
    }

    unsigned short* outq = outv + (size_t)z * 4194304;
    if (z < 2) {
        const int hq = (n0 + wn) >> 6;               // head (constant per thread)
        float freq[2];
#pragma unroll
        for (int in = 0; in < 2; ++in)
            freq[in] = exp2f(-(float)(in * 16 + l) * 0.41524101186f);  // log2(10000)/32
#pragma unroll
        for (int im = 0; im < 2; ++im)
#pragma unroll
            for (int i = 0; i < 4; ++i) {
                const int m = m0 + wm + im * 16 + g * 4 + i;
                const int b = m >> 11, t = m & 2047;
                float fw = 1.0f;
                if (z == 1) fw = 0.18033688011f * swg[(b << 11) + t];  // SCALE*log2(e)*w
                const size_t fq = (size_t)((b << 4) + hq) * 131072
                                + (size_t)((t >> 5) << 2) * 512
                                + (size_t)((((l >> 3) & 1) << 5) + (t & 31)) * 8 + (l & 7);
#pragma unroll
                for (int in = 0; in < 2; ++in) {
                    const float ang = (float)t * freq[in];
                    const float cs2 = __cosf(ang), sn = __sinf(ang);
                    const float x1 = acc[im][in][i], x2 = acc[im][in + 2][i];
                    outq[fq + (size_t)in * 512]       = f2bf((x1 * cs2 - x2 * sn) * fw);
                    outq[fq + (size_t)(in + 2) * 512] = f2bf((x2 * cs2 + x1 * sn) * fw);
                }
            }
    } else {
        // V fragments: 4 consecutive t -> 4 consecutive slots within one lane group -> ushort4
#pragma unroll
        for (int im = 0; im < 2; ++im)
#pragma unroll
            for (int in = 0; in < 4; ++in) {
                const int n = n0 + wn + in * 16 + l;
                const int h = n >> 6, d = n & 63;
                const int mb = m0 + wm + im * 16 + g * 4;
                const int bq = mb >> 11, t0 = mb & 2047;
                ushort4 pk;
                pk.x = f2bf(acc[im][in][0]); pk.y = f2bf(acc[im][in][1]);
                pk.z = f2bf(acc[im][in][2]); pk.w = f2bf(acc[im][in][3]);
                const size_t fv = (size_t)((bq << 4) + h) * 131072
                                + (size_t)(((t0 >> 5) << 2) + ((d >> 5) << 1) + ((t0 >> 4) & 1)) * 512
                                + (size_t)((((t0 >> 3) & 1) << 5) + (d & 31)) * 8 + (t0 & 7);
                *(ushort4*)&outq[fv] = pk;
            }
    }
}

// Projection: C = A(bf16)[4096,1024] x Wo^T + bias, 64x128 tile -> 512 blocks.
// 3-buffer counted-vmcnt pipeline (3 loads/thread/stage -> vmcnt(3)).
__global__ __launch_bounds__(256) void gemm_proj(
    const unsigned short* __restrict__ A, const unsigned short* __restrict__ W,
    float* __restrict__ out, const float* __restrict__ bias)
{
    constexpr int K = 1024, BK = 32, NS = K / BK;
    __shared__ __align__(16) unsigned short As[3][64 * BK];
    __shared__ __align__(16) unsigned short Bs[3][128 * BK];
    const int tid = threadIdx.x;
    const int wid = tid >> 6, lane = tid & 63, g = lane >> 4, l = lane & 15;
    const int wm = (wid & 1) * 32, wn = (wid >> 1) * 64;

    const int lin = blockIdx.x + (blockIdx.y << 3);     // 512 blocks, 512%8==0
    const int wg  = (lin & 7) * 64 + (lin >> 3);
    const int m0 = (wg >> 3) * 64, n0 = (wg & 7) * 128;

    f32x4 acc[2][4];
#pragma unroll
    for (int i = 0; i < 2; ++i)
#pragma unroll
        for (int j = 0; j < 4; ++j) acc[i][j] = f32x4{0.f, 0.f, 0.f, 0.f};

    const int r = tid >> 2;
    const int c = (tid & 3) * 8;

    auto stage = [&](int buf, int k0) {
        async16(&A[(size_t)(m0 + r) * K + k0 + c], &As[buf][wid * 512]);
        unsigned short* BsW = &Bs[buf][wid * 512];
        async16(&W[(size_t)(n0 + r) * K + k0 + c], BsW);
        async16(&W[(size_t)(n0 + 64 + r) * K + k0 + c], BsW + 2048);
    };

    stage(0, 0);
    stage(1, BK);
    for (int ks = 0; ks < NS; ++ks) {
        if (ks + 1 < NS) asm volatile("s_waitcnt vmcnt(3)" ::: "memory");
        else             asm volatile("s_waitcnt vmcnt(0)" ::: "memory");
        __builtin_amdgcn_s_barrier();
        const unsigned short* Asr = As[ks % 3];
        const unsigned short* Bsr = Bs[ks % 3];
        bf16x8 af[2], bfr[4];
#pragma unroll
        for (int im = 0; im < 2; ++im) af[im]  = *(const bf16x8*)&Asr[(wm + im * 16 + l) * BK + g * 8];
#pragma unroll
        for (int in = 0; in < 4; ++in) bfr[in] = *(const bf16x8*)&Bsr[(wn + in * 16 + l) * BK + g * 8];
#pragma unroll
        for (int im = 0; im < 2; ++im)
#pragma unroll
            for (int in = 0; in < 4; ++in)
                acc[im][in] = __builtin_amdgcn_mfma_f32_16x16x32_bf16(af[im], bfr[in], acc[im][in], 0, 0, 0);
        if (ks + 2 < NS) stage((ks + 2) % 3, (ks + 2) * BK);
    }

#pragma unroll
    for (int im = 0; im < 2; ++im)
#pragma unroll
        for (int in = 0; in < 4; ++in) {
            const int n = n0 + wn + in * 16 + l;
#pragma unroll
            for (int i = 0; i < 4; ++i) {
                const int m = m0 + wm + im * 16 + g * 4 + i;
                out[(size_t)m * 1024 + n] = acc[im][in][i] + bias[n];
            }
        }
}

// Flash v6: 2048 blocks x 128 threads, block = (bh, 32q strip p), longest-first.
// NO LDS staging, NO barriers in the loop: Q/K/V pre-fragmented so each MFMA operand
// is one coalesced 16B/lane global load (L2/L3-resident). Wave wid owns key chunks
// c = wid, wid+2, ... <= p. Swapped QK^T -> in-register softmax (16 exp2 + 8 cvt_pk
// + 4 permlane32_swap). K pre-scaled by SCALE*log2e*w[key]. Constant-max softmax ->
// the two waves' partials combine additively once at the end (12KB LDS).
__global__ __launch_bounds__(128, 2) void flash_attn(
    const unsigned short* __restrict__ Qf, const unsigned short* __restrict__ Kf,
    const unsigned short* __restrict__ Vf, const float* __restrict__ sbias,
    const float* __restrict__ sw, unsigned short* __restrict__ attn)
{
    constexpr int T = 2048;
    __shared__ float Cmb[3072];             // 2x16x64 oacc + 16x64 lrow = 12 KB

    const int tid = threadIdx.x, wid = tid >> 6, lane = tid & 63;
    const int hl = lane & 31, hh = lane >> 5;
    const int id = blockIdx.x;
    const int p  = 63 - (id >> 5);          // globally longest-first
    const int bh = id & 31, b = bh >> 4, h = bh & 15;
    const size_t fb = (size_t)bh * 131072;  // fragment base (Q/K/V identical shape)
    const float bias = sbias[h];
    const float* swb = sw + b * T;

    bf16x8 onef;
#pragma unroll
    for (int j = 0; j < 8; ++j) onef[j] = (__bf16)1.0f;

    const int q0 = p * 32;
    bf16x8 qf[4];
#pragma unroll
    for (int ks = 0; ks < 4; ++ks)
        qf[ks] = *(const bf16x8*)&Qf[fb + (size_t)(p * 4 + ks) * 512 + lane * 8];

    f32x16 oacc[2], lrow;
#pragma unroll
    for (int r = 0; r < 16; ++r) { oacc[0][r] = 0.f; oacc[1][r] = 0.f; lrow[r] = 0.f; }

    for (int c = wid; c <= p; c += 2) {
        const unsigned short* kb = &Kf[fb + (size_t)c * 2048 + lane * 8];
        const unsigned short* vb = &Vf[fb + (size_t)c * 2048 + lane * 8];

        // S^T = K' Q^T (32k x 32q): lane holds q = q0+hl, rows r -> keys
        const bf16x8 kf0 = *(const bf16x8*)&kb[0];
        const bf16x8 kf1 = *(const bf16x8*)&kb[512];
        const bf16x8 kf2 = *(const bf16x8*)&kb[1024];
        const bf16x8 kf3 = *(const bf16x8*)&kb[1536];
        f32x16 sx;
#pragma unroll
        for (int r = 0; r < 16; ++r) sx[r] = 0.f;
        sx = __builtin_amdgcn_mfma_f32_32x32x16_bf16(kf0, qf[0], sx, 0, 0, 0);
        sx = __builtin_amdgcn_mfma_f32_32x32x16_bf16(kf1, qf[1], sx, 0, 0, 0);
        sx = __builtin_amdgcn_mfma_f32_32x32x16_bf16(kf2, qf[2], sx, 0, 0, 0);
        sx = __builtin_amdgcn_mfma_f32_32x32x16_bf16(kf3, qf[3], sx, 0, 0, 0);

        // issue V loads now; softmax below covers their L2 latency
        const bf16x8 vf00 = *(const bf16x8*)&vb[0];      // (dt0,ks0)
        const bf16x8 vf01 = *(const bf16x8*)&vb[512];    // (dt0,ks1)
        const bf16x8 vf10 = *(const bf16x8*)&vb[1024];   // (dt1,ks0)
        const bf16x8 vf11 = *(const bf16x8*)&vb[1536];   // (dt1,ks1)

        if (bias != 0.0f) {                  // benchmark has sector_bias == 0
            const float bn = bias * 1.44269504f;
#pragma unroll
            for (int r = 0; r < 16; ++r) {
                const int kl = (r & 3) + 8 * (r >> 2) + 4 * hh;
                sx[r] += bn * swb[c * 32 + kl];
            }
        }
        if (c == p) {                        // diagonal chunk: causal mask (key kl <= q hl)
#pragma unroll
            for (int r = 0; r < 16; ++r) {
                const int kl = (r & 3) + 8 * (r >> 2) + 4 * hh;
                sx[r] = (kl <= hl) ? sx[r] : -1e30f;
            }
        }
#pragma unroll
        for (int r = 0; r < 16; ++r) sx[r] = exp2f(sx[r]);

        // pack P -> bf16 A-fragment: 8 cvt_pk + 4 permlane32_swap
        unsigned wds[8];
#pragma unroll
        for (int g2 = 0; g2 < 4; ++g2) {
            wds[g2 * 2]     = cvtpk(sx[g2 * 4],     sx[g2 * 4 + 1]);
            wds[g2 * 2 + 1] = cvtpk(sx[g2 * 4 + 2], sx[g2 * 4 + 3]);
        }
        bf16x8 pf[2];
#pragma unroll
        for (int ks = 0; ks < 2; ++ks) {
            unsigned a0, a1, b0, b1;
            plswap(wds[4 * ks],     wds[4 * ks + 2], a0, a1);
            plswap(wds[4 * ks + 1], wds[4 * ks + 3], b0, b1);
            union { unsigned u[4]; bf16x8 v; } pk_;
            pk_.u[0] = a0; pk_.u[1] = b0;
            pk_.u[2] = a1; pk_.u[3] = b1;
            pf[ks] = pk_.v;
        }

        // rowsum via ones-MFMA, accumulated straight into lrow
        lrow = __builtin_amdgcn_mfma_f32_32x32x16_bf16(pf[0], onef, lrow, 0, 0, 0);
        lrow = __builtin_amdgcn_mfma_f32_32x32x16_bf16(pf[1], onef, lrow, 0, 0, 0);

        // O += P V
        oacc[0] = __builtin_amdgcn_mfma_f32_32x32x16_bf16(pf[0], vf00, oacc[0], 0, 0, 0);
        oacc[0] = __builtin_amdgcn_mfma_f32_32x32x16_bf16(pf[1], vf01, oacc[0], 0, 0, 0);
        oacc[1] = __builtin_amdgcn_mfma_f32_32x32x16_bf16(pf[0], vf10, oacc[1], 0, 0, 0);
        oacc[1] = __builtin_amdgcn_mfma_f32_32x32x16_bf16(pf[1], vf11, oacc[1], 0, 0, 0);
    }

    // combine the two waves' partials (additive under constant-max softmax)
    __syncthreads();
    if (wid == 1) {
#pragma unroll
        for (int dt = 0; dt < 2; ++dt)
#pragma unroll
            for (int r = 0; r < 16; ++r) Cmb[(dt * 16 + r) * 64 + lane] = oacc[dt][r];
#pragma unroll
        for (int r = 0; r < 16; ++r) Cmb[2048 + r * 64 + lane] = lrow[r];
    }
    __syncthreads();
    if (wid == 0) {
#pragma unroll
        for (int r = 0; r < 16; ++r) {
            const float li = 1.0f / (lrow[r] + Cmb[2048 + r * 64 + lane]);
            const int row = (r & 3) + 8 * (r >> 2) + 4 * hh;
            const int qr = q0 + row;
#pragma unroll
            for (int dt = 0; dt < 2; ++dt) {
                const float ov = oacc[dt][r] + Cmb[(dt * 16 + r) * 64 + lane];
                attn[(size_t)(b * T + qr) * 1024 + h * 64 + dt * 32 + hl] = f2bf(ov * li);
            }
        }
    }
}

extern "C" void kernel_launch(void* const* d_in, const int* in_sizes, int n_in,
                              void* d_out, int out_size, void* d_ws, size_t ws_size,
                              hipStream_t stream) {
    const float* x  = (const float*)d_in[0];
    const float* Wq = (const float*)d_in[1];
    const float* Wk = (const float*)d_in[2];
    const float* Wv = (const float*)d_in[3];
    const float* Wo = (const float*)d_in[4];
    const float* bo = (const float*)d_in[5];
    const float* sb = (const float*)d_in[6];
    const float* sw = (const float*)d_in[7];

    const size_t QKV_SZ = 4194304;   // shorts per q/k/v tensor
    const size_t W_SZ   = 1048576;   // shorts per weight matrix
    unsigned short* ws16 = (unsigned short*)d_ws;
    const bool big = ws_size >= 2 * (4 * QKV_SZ + 4 * W_SZ);  // 41.9 MB

    if (big) {
        unsigned short* xb    = ws16;            // x bf16
        unsigned short* Wb3   = xb + QKV_SZ;     // Wq,Wk,Wv
        unsigned short* Wob   = Wb3 + 3 * W_SZ;  // Wo
        unsigned short* qkv   = Wob + W_SZ;      // q,k,v (flash-fragment-major)
        unsigned short* attnb = xb;              // overlay x (dead after QKV gemm)

        cvt_all<<<4096, 256, 0, stream>>>(x, Wq, Wk, Wv, Wo, xb, 1, 1048576);
        gemm_qkv<1><<<dim3(8, 32, 3), 512, 0, stream>>>(xb, Wb3, qkv, sw);
        flash_attn<<<2048, 128, 0, stream>>>(qkv, qkv + QKV_SZ, qkv + 2 * QKV_SZ,
                                             sb, sw, attnb);
        gemm_proj<<<dim3(8, 64), 256, 0, stream>>>(attnb, Wob, (float*)d_out, bo);
    } else {                                     // 33.6 MB fallback
        unsigned short* qkv   = ws16;
        unsigned short* attnb = qkv + 3 * QKV_SZ;
        unsigned short* Wb3   = attnb;           // overlay attn (dead until flash)
        unsigned short* Wob   = qkv;             // overlay q (dead after flash)

        cvt_all<<<1536, 256, 0, stream>>>(x, Wq, Wk, Wv, Wo, Wb3, 0, 393216);
        gemm_qkv<0><<<dim3(8, 32, 3), 512, 0, stream>>>(x, Wb3, qkv, sw);
        flash_attn<<<2048, 128, 0, stream>>>(qkv, qkv + QKV_SZ, qkv + 2 * QKV_SZ,
                                             sb, sw, attnb);
        cvt_all<<<512, 256, 0, stream>>>(x, Wo, Wo, Wo, Wo, Wob, 0, 131072);
        gemm_proj<<<dim3(8, 64), 256, 0, stream>>>(attnb, Wob, (float*)d_out, bo);
    }
}